// Round 4
// baseline (18089.885 us; speedup 1.0000x reference)
//
#include <hip/hip_runtime.h>

// ---------------- helpers ----------------
__device__ __forceinline__ float sigm(float x) {
    return 1.0f / (1.0f + __expf(-x));
}
__device__ __forceinline__ float tanh_(float x) {
    return 1.0f - 2.0f / (1.0f + __expf(2.0f * x));
}
__device__ __forceinline__ unsigned int packbf2(float a, float b) {
    unsigned int ua = __float_as_uint(a);
    ua = (ua + 0x7fffu + ((ua >> 16) & 1u)) >> 16;
    unsigned int ub = __float_as_uint(b);
    ub = (ub + 0x7fffu + ((ub >> 16) & 1u)) >> 16;
    return ua | (ub << 16);
}
__device__ __forceinline__ float blo(unsigned int u) { return __uint_as_float(u << 16); }
__device__ __forceinline__ float bhi(unsigned int u) { return __uint_as_float(u & 0xffff0000u); }

// Force register residency: compiler can't rematerialize asm-"modified" values (rule #17).
#define PIN4(v) asm volatile("" : "+v"((v).x), "+v"((v).y), "+v"((v).z), "+v"((v).w))
#define PIN(v)  asm volatile("" : "+v"(v))

// ---------------- LSTM layer 1 (bidirectional, fused input projection K=40) ----------------
__global__ __launch_bounds__(512, 2) void lstm1_k(
    const float* __restrict__ utter,
    const float* __restrict__ wih_f, const float* __restrict__ whh_f,
    const float* __restrict__ bih_f, const float* __restrict__ bhh_f,
    const float* __restrict__ wih_r, const float* __restrict__ whh_r,
    const float* __restrict__ bih_r, const float* __restrict__ bhh_r,
    float* __restrict__ Hf, float* __restrict__ Hr)
{
    const int tid = threadIdx.x;
    const int b   = blockIdx.x & 63;
    const int dir = blockIdx.x >> 6;
    const float* wih = dir ? wih_r : wih_f;
    const float* whh = dir ? whh_r : whh_f;
    const float* bih = dir ? bih_r : bih_f;
    const float* bhh = dir ? bhh_r : bhh_f;
    float* Hout = dir ? Hr : Hf;

    __shared__ __align__(16) float h_lds[128];
    __shared__ float gates[512];
    __shared__ __align__(16) float x3[3][48];

    const int j = tid;
    float4 wr[32];
    {
        const float4* wp = reinterpret_cast<const float4*>(whh + j * 128);
#pragma unroll
        for (int m = 0; m < 32; ++m) wr[m] = wp[m];
    }
#pragma unroll
    for (int m = 0; m < 32; ++m) PIN4(wr[m]);
    float4 wx[10];
    {
        const float4* xp = reinterpret_cast<const float4*>(wih + j * 40);
#pragma unroll
        for (int q = 0; q < 10; ++q) wx[q] = xp[q];
    }
#pragma unroll
    for (int q = 0; q < 10; ++q) PIN4(wx[q]);
    const float bias = bih[j] + bhh[j];
    float c = 0.0f;
    if (tid < 128) h_lds[tid] = 0.0f;
    if (tid < 40) {
        int tt0 = dir ? 2047 : 0;
        x3[0][tid] = utter[((size_t)b * 2048 + tt0) * 40 + tid];
    } else if (tid < 80) {
        int tt1 = dir ? 2046 : 1;
        x3[1][tid - 40] = utter[((size_t)b * 2048 + tt1) * 40 + (tid - 40)];
    }
    __syncthreads();

    for (int t = 0; t < 2048; ++t) {
        const int cur = t % 3;
        const int nx2 = (t + 2) % 3;
        float xn = 0.0f;
        const int tq = tid - 128;
        if (tq >= 0 && tq < 40) {
            int tn = (t + 2 < 2048) ? (t + 2) : 2047;
            int ttn = dir ? (2047 - tn) : tn;
            xn = utter[((size_t)b * 2048 + ttn) * 40 + tq];
        }
        float g = bias;
        const float4* x4 = reinterpret_cast<const float4*>(&x3[cur][0]);
#pragma unroll
        for (int q = 0; q < 10; ++q) {
            float4 x = x4[q];
            g += wx[q].x * x.x + wx[q].y * x.y + wx[q].z * x.z + wx[q].w * x.w;
        }
        const float4* h4 = reinterpret_cast<const float4*>(h_lds);
#pragma unroll
        for (int m = 0; m < 32; ++m) {
            float4 h = h4[m];
            g += wr[m].x * h.x + wr[m].y * h.y + wr[m].z * h.z + wr[m].w * h.w;
        }
        gates[j] = g;
        __syncthreads();
        if (tid < 128) {
            float i_ = sigm(gates[tid]);
            float f_ = sigm(gates[128 + tid]);
            float g_ = tanh_(gates[256 + tid]);
            float o_ = sigm(gates[384 + tid]);
            c = f_ * c + i_ * g_;
            float hh = o_ * tanh_(c);
            h_lds[tid] = hh;
            int tt = dir ? (2047 - t) : t;
            Hout[((size_t)tt * 64 + b) * 128 + tid] = hh;
        } else if (tq < 40) {
            x3[nx2][tq] = xn;
        }
        __syncthreads();
    }
}

// ---------------- LSTM layers 2/3 (P precomputed incl. biases) ----------------
__global__ __launch_bounds__(512, 2) void lstm_k(
    const float* __restrict__ P, const float* __restrict__ whh,
    float* __restrict__ Hout, int T)
{
    const int tid = threadIdx.x;
    const int b = blockIdx.x;
    const int j = tid;
    __shared__ __align__(16) float h_lds[128];
    __shared__ float gates[512];
    float4 wr[32];
    {
        const float4* wp = reinterpret_cast<const float4*>(whh + j * 128);
#pragma unroll
        for (int m = 0; m < 32; ++m) wr[m] = wp[m];
    }
#pragma unroll
    for (int m = 0; m < 32; ++m) PIN4(wr[m]);
    float c = 0.0f;
    if (tid < 128) h_lds[tid] = 0.0f;
    float p_cur = P[((size_t)b * T + 0) * 512 + j];
    float p_n1  = P[((size_t)b * T + ((T > 1) ? 1 : 0)) * 512 + j];
    __syncthreads();
    for (int t = 0; t < T; ++t) {
        int tn = (t + 2 < T) ? (t + 2) : (T - 1);
        float p_n2 = P[((size_t)b * T + tn) * 512 + j];
        float g = p_cur;
        const float4* h4 = reinterpret_cast<const float4*>(h_lds);
#pragma unroll
        for (int m = 0; m < 32; ++m) {
            float4 h = h4[m];
            g += wr[m].x * h.x + wr[m].y * h.y + wr[m].z * h.z + wr[m].w * h.w;
        }
        gates[j] = g;
        __syncthreads();
        if (tid < 128) {
            float i_ = sigm(gates[tid]);
            float f_ = sigm(gates[128 + tid]);
            float g_ = tanh_(gates[256 + tid]);
            float o_ = sigm(gates[384 + tid]);
            c = f_ * c + i_ * g_;
            float hh = o_ * tanh_(c);
            h_lds[tid] = hh;
            Hout[((size_t)t * 64 + b) * 128 + tid] = hh;
        }
        __syncthreads();
        p_cur = p_n1;
        p_n1 = p_n2;
    }
}

// ---------------- conv1d kernel=2 stride=2 ----------------
template <int CIN>
__global__ __launch_bounds__(128) void conv_k(
    const float* __restrict__ HA, const float* __restrict__ HB,
    const float* __restrict__ W, const float* __restrict__ bias,
    float* __restrict__ out, int Tout)
{
    __shared__ __align__(16) float xin[64 * CIN];
    const int b = blockIdx.x;
    const int t0 = blockIdx.y * 32;
    const int tid = threadIdx.x;
    for (int idx = tid; idx < 64 * CIN; idx += 128) {
        int tl = idx / CIN, ci = idx % CIN;
        int tau = t0 * 2 + tl;
        float v;
        if constexpr (CIN == 256) {
            v = (ci < 128) ? HA[(size_t)tau * 8192 + b * 128 + ci]
                           : HB[(size_t)tau * 8192 + b * 128 + (ci - 128)];
        } else {
            v = HA[(size_t)tau * 8192 + b * 128 + ci];
        }
        xin[idx] = v;
    }
    __syncthreads();
    const int co = tid;
    float acc[32];
#pragma unroll
    for (int u = 0; u < 32; ++u) acc[u] = 0.0f;
    const float4* Wrow4 = reinterpret_cast<const float4*>(W + (size_t)co * 2 * CIN);
    const float4* xin4 = reinterpret_cast<const float4*>(xin);
    for (int c4 = 0; c4 < CIN / 4; ++c4) {
        float4 wA = Wrow4[2 * c4];
        float4 wB = Wrow4[2 * c4 + 1];
#pragma unroll
        for (int u = 0; u < 32; ++u) {
            float4 x0 = xin4[(2 * u) * (CIN / 4) + c4];
            float4 x1 = xin4[(2 * u + 1) * (CIN / 4) + c4];
            acc[u] += wA.x * x0.x + wA.y * x1.x + wA.z * x0.y + wA.w * x1.y
                    + wB.x * x0.z + wB.y * x1.z + wB.z * x0.w + wB.w * x1.w;
        }
    }
    float bs = bias[co];
#pragma unroll
    for (int u = 0; u < 32; ++u)
        out[((size_t)b * Tout + t0 + u) * 128 + co] = acc[u] + bs;
}

// ---------------- generic f32 GEMM ----------------
// mode 0: C[m*N+n]; mode 1: m=(t*64+b) -> C[(b*N+n)*Tdim + t]
__global__ __launch_bounds__(256) void gemm_k(
    const float* __restrict__ A, const float* __restrict__ W, int ldw,
    const float* __restrict__ bias1, const float* __restrict__ bias2,
    float* __restrict__ C, int M, int N, int K, int mode, int Tdim)
{
    __shared__ __align__(16) float As[16][68];
    __shared__ __align__(16) float Ws[16][68];
    const int tid = threadIdx.x;
    const int m0 = blockIdx.x * 64, n0 = blockIdx.y * 64;
    const int kk = tid & 15, mm = tid >> 4;
    const int tm = tid & 15, tn = tid >> 4;
    float acc[4][4];
#pragma unroll
    for (int i = 0; i < 4; ++i)
#pragma unroll
        for (int jj = 0; jj < 4; ++jj) acc[i][jj] = 0.0f;

    for (int k0 = 0; k0 < K; k0 += 16) {
#pragma unroll
        for (int r = 0; r < 4; ++r) {
            As[kk][mm + 16 * r] = A[(size_t)(m0 + mm + 16 * r) * K + k0 + kk];
            Ws[kk][mm + 16 * r] = W[(size_t)(n0 + mm + 16 * r) * ldw + k0 + kk];
        }
        __syncthreads();
#pragma unroll
        for (int q = 0; q < 16; ++q) {
            float4 a = reinterpret_cast<const float4*>(&As[q][0])[tm];
            float4 w = reinterpret_cast<const float4*>(&Ws[q][0])[tn];
            acc[0][0] += a.x * w.x; acc[0][1] += a.x * w.y; acc[0][2] += a.x * w.z; acc[0][3] += a.x * w.w;
            acc[1][0] += a.y * w.x; acc[1][1] += a.y * w.y; acc[1][2] += a.y * w.z; acc[1][3] += a.y * w.w;
            acc[2][0] += a.z * w.x; acc[2][1] += a.z * w.y; acc[2][2] += a.z * w.z; acc[2][3] += a.z * w.w;
            acc[3][0] += a.w * w.x; acc[3][1] += a.w * w.y; acc[3][2] += a.w * w.z; acc[3][3] += a.w * w.w;
        }
        __syncthreads();
    }
    float bv[4];
#pragma unroll
    for (int jj = 0; jj < 4; ++jj) {
        int n = n0 + tn * 4 + jj;
        float v = 0.0f;
        if (bias1) v += bias1[n];
        if (bias2) v += bias2[n];
        bv[jj] = v;
    }
#pragma unroll
    for (int i = 0; i < 4; ++i) {
        int m = m0 + tm * 4 + i;
#pragma unroll
        for (int jj = 0; jj < 4; ++jj) {
            int n = n0 + tn * 4 + jj;
            float v = acc[i][jj] + bv[jj];
            if (mode == 0) {
                C[(size_t)m * N + n] = v;
            } else {
                int bb = m & 63, tt = m >> 6;
                C[((size_t)bb * N + n) * Tdim + tt] = v;
            }
        }
    }
}

// ---------------- gather emb[targets] rows ----------------
__global__ __launch_bounds__(512) void packemb_k(
    const int* __restrict__ targets, const float* __restrict__ emb,
    float* __restrict__ Ypack)
{
    int m = blockIdx.x;  // l*64 + b
    int l = m >> 6, b = m & 63;
    int tgt = targets[b * 256 + l];
    Ypack[(size_t)m * 512 + threadIdx.x] = emb[(size_t)tgt * 512 + threadIdx.x];
}

// ---------------- pack hvT f32 [b][d][t] -> bf16 pairs [b][d][t/2] ----------------
__global__ __launch_bounds__(256) void packhv_k(
    const float* __restrict__ hvT, unsigned int* __restrict__ hvpak)
{
    int b = blockIdx.x, d = blockIdx.y, i = threadIdx.x;
    const float2 v = reinterpret_cast<const float2*>(hvT + ((size_t)b * 128 + d) * 512)[i];
    hvpak[((size_t)b * 128 + d) * 256 + i] = packbf2(v.x, v.y);
}

// ---------------- attention decoder v3: one WG per batch, 255 steps ----------------
// whhd row f32 in regs (pinned), wc row bf16 in regs (pinned), hk bf16 in LDS,
// hv streamed from L2 as bf16 pairs. 7 barriers/step, no max-sub in att softmax,
// att normalization deferred to context.
__global__ __launch_bounds__(512, 2) void decoder_k(
    const float* __restrict__ Yp, const float* __restrict__ whhd, const float* __restrict__ wihd,
    const float* __restrict__ hk,            // f32 [t*64+b][128]
    const unsigned int* __restrict__ hvpak,  // [b][128][256] bf16 pairs over t
    const float* __restrict__ w1, const float* __restrict__ b1,
    const float* __restrict__ w2, const float* __restrict__ b2,
    const float* __restrict__ w3, const float* __restrict__ b3,
    const float* __restrict__ sh0, const float* __restrict__ sc0,
    float* __restrict__ out)
{
    __shared__ unsigned int hk_lds[512][66];   // 135,168 B; stride 66 words -> 2-way free
    __shared__ __align__(16) float sh_lds[128];
    __shared__ __align__(16) float sc_lds[128];
    __shared__ __align__(16) float c_lds[128];
    __shared__ float gates[512];
    __shared__ __align__(16) float att[512];
    __shared__ float red[8];
    __shared__ float out_lds[34];
    __shared__ float z_lds[34];

    const int tid = threadIdx.x;
    const int b = blockIdx.x;

    // whhd row tid: f32 in regs, pinned (128 VGPRs)
    float4 wr[32];
    {
        const float4* wp = reinterpret_cast<const float4*>(whhd + tid * 128);
#pragma unroll
        for (int m = 0; m < 32; ++m) wr[m] = wp[m];
    }
#pragma unroll
    for (int m = 0; m < 32; ++m) PIN4(wr[m]);
    // wc row tid (wihd cols 512..639): bf16 pairs in regs, pinned (64 VGPRs)
    unsigned int wcp[64];
    {
        const float4* cp = reinterpret_cast<const float4*>(wihd + (size_t)tid * 640 + 512);
#pragma unroll
        for (int q = 0; q < 32; ++q) {
            float4 v = cp[q];
            wcp[2 * q]     = packbf2(v.x, v.y);
            wcp[2 * q + 1] = packbf2(v.z, v.w);
        }
    }
#pragma unroll
    for (int q = 0; q < 64; ++q) PIN(wcp[q]);
    // hk row t=tid -> LDS bf16
    {
        const float4* hp = reinterpret_cast<const float4*>(hk + ((size_t)tid * 64 + b) * 128);
#pragma unroll
        for (int q = 0; q < 32; ++q) {
            float4 v = hp[q];
            *reinterpret_cast<uint2*>(&hk_lds[tid][2 * q]) =
                make_uint2(packbf2(v.x, v.y), packbf2(v.z, v.w));
        }
    }
    float sc_r = 0.0f;
    if (tid < 128) {
        sh_lds[tid] = sh0[b * 128 + tid];
        sc_r = sc0[b * 128 + tid];
        sc_lds[tid] = sc_r;
        c_lds[tid] = 0.0f;
    }
    __syncthreads();

    const int wid = tid >> 6, lane = tid & 63;
    const int g4 = tid >> 7, d = tid & 127;
    const uint4* hvr = reinterpret_cast<const uint4*>(hvpak + ((size_t)b * 128 + d) * 256 + g4 * 64);
    float yp_cur = Yp[(size_t)(0 * 64 + b) * 512 + tid];

    for (int l = 0; l < 255; ++l) {
        int lnxt = (l + 1 < 255) ? (l + 1) : l;
        float yp_nxt = Yp[(size_t)(lnxt * 64 + b) * 512 + tid];
        // ---- phase 1: gates = Yp + sh@whhd.T + c@wc.T
        float g = yp_cur;
        {
            const float4* sh4 = reinterpret_cast<const float4*>(sh_lds);
#pragma unroll
            for (int q = 0; q < 32; ++q) {
                float4 h = sh4[q];
                g += wr[q].x * h.x + wr[q].y * h.y + wr[q].z * h.z + wr[q].w * h.w;
            }
            const float4* c4 = reinterpret_cast<const float4*>(c_lds);
#pragma unroll
            for (int q = 0; q < 32; ++q) {
                float4 cc = c4[q];
                unsigned int u0 = wcp[2 * q], u1 = wcp[2 * q + 1];
                g += blo(u0) * cc.x + bhi(u0) * cc.y + blo(u1) * cc.z + bhi(u1) * cc.w;
            }
        }
        gates[tid] = g;
        __syncthreads();                                   // B1
        // ---- phase 2: cell update
        if (tid < 128) {
            float i_ = sigm(gates[tid]);
            float f_ = sigm(gates[128 + tid]);
            float g_ = tanh_(gates[256 + tid]);
            float o_ = sigm(gates[384 + tid]);
            sc_r = f_ * sc_r + i_ * g_;
            float hh = o_ * tanh_(sc_r);
            sh_lds[tid] = hh;
            sc_lds[tid] = sc_r;
        }
        __syncthreads();                                   // B2
        // ---- phase 3: scores (thread t), exp without max-sub, wave-sum
        float e = 0.0f;
        {
            const uint2* hkr = reinterpret_cast<const uint2*>(&hk_lds[tid][0]);
            const float4* sc4 = reinterpret_cast<const float4*>(sc_lds);
#pragma unroll
            for (int q = 0; q < 32; ++q) {
                uint2 u = hkr[q];
                float4 s = sc4[q];
                e += blo(u.x) * s.x + bhi(u.x) * s.y + blo(u.y) * s.z + bhi(u.y) * s.w;
            }
        }
        float p = __expf(e);
        att[tid] = p;
        float ps = p;
#pragma unroll
        for (int off = 32; off; off >>= 1) ps += __shfl_xor(ps, off);
        if (lane == 0) red[wid] = ps;
        __syncthreads();                                   // B3 (att + red visible)
        float S = ((red[0] + red[1]) + (red[2] + red[3]))
                + ((red[4] + red[5]) + (red[6] + red[7]));
        // ---- phase 4: context partials (raw p), thread (g4, d)
        {
            const float4* att4 = reinterpret_cast<const float4*>(att);
            float acc = 0.0f;
#pragma unroll
            for (int q = 0; q < 16; ++q) {
                uint4 u = hvr[q];
                float4 a0 = att4[g4 * 32 + 2 * q];
                float4 a1 = att4[g4 * 32 + 2 * q + 1];
                acc += blo(u.x) * a0.x + bhi(u.x) * a0.y + blo(u.y) * a0.z + bhi(u.y) * a0.w
                     + blo(u.z) * a1.x + bhi(u.z) * a1.y + blo(u.w) * a1.z + bhi(u.w) * a1.w;
            }
            gates[tid] = acc;
        }
        __syncthreads();                                   // B4
        if (tid < 128)
            c_lds[tid] = (gates[tid] + gates[128 + tid] + gates[256 + tid] + gates[384 + tid]) / S;
        __syncthreads();                                   // B5
        // ---- phase 5: output head (34 threads)
        if (tid < 34) {
            float o1 = b1[tid] + b2[tid];
            const float4* w1r = reinterpret_cast<const float4*>(w1 + tid * 128);
            const float4* w2r = reinterpret_cast<const float4*>(w2 + tid * 128);
            const float4* sh4 = reinterpret_cast<const float4*>(sh_lds);
            const float4* c4 = reinterpret_cast<const float4*>(c_lds);
#pragma unroll 8
            for (int q = 0; q < 32; ++q) {
                float4 a = w1r[q], bb2 = w2r[q], h = sh4[q], cc = c4[q];
                o1 += a.x * h.x + a.y * h.y + a.z * h.z + a.w * h.w
                    + bb2.x * cc.x + bb2.y * cc.y + bb2.z * cc.z + bb2.w * cc.w;
            }
            out_lds[tid] = fmaxf(o1, 0.0f);
        }
        __syncthreads();                                   // B6
        if (tid < 34) {
            float z = b3[tid];
            const float* w3r = w3 + tid * 34;
            for (int v = 0; v < 34; ++v) z += out_lds[v] * w3r[v];
            z_lds[tid] = z;
        }
        __syncthreads();                                   // B7
        if (tid < 34) {
            float zm = z_lds[0];
            for (int v = 1; v < 34; ++v) zm = fmaxf(zm, z_lds[v]);
            float Ssum = 0.0f;
            for (int v = 0; v < 34; ++v) Ssum += __expf(z_lds[v] - zm);
            out[((size_t)b * 255 + l) * 34 + tid] = __expf(z_lds[tid] - zm) / Ssum;
        }
        yp_cur = yp_nxt;
    }
}

// ---------------- launch ----------------
extern "C" void kernel_launch(void* const* d_in, const int* in_sizes, int n_in,
                              void* d_out, int out_size, void* d_ws, size_t ws_size,
                              hipStream_t stream) {
    (void)in_sizes; (void)n_in; (void)out_size; (void)ws_size;
    const float* utter = (const float*)d_in[0];
    const int*   targets = (const int*)d_in[1];
    const float* wih_f = (const float*)d_in[2];
    const float* whh_f = (const float*)d_in[3];
    const float* bih_f = (const float*)d_in[4];
    const float* bhh_f = (const float*)d_in[5];
    const float* wih_r = (const float*)d_in[6];
    const float* whh_r = (const float*)d_in[7];
    const float* bih_r = (const float*)d_in[8];
    const float* bhh_r = (const float*)d_in[9];
    const float* c1w = (const float*)d_in[10];
    const float* c1b = (const float*)d_in[11];
    const float* wih1 = (const float*)d_in[12];
    const float* whh1 = (const float*)d_in[13];
    const float* bih1 = (const float*)d_in[14];
    const float* bhh1 = (const float*)d_in[15];
    const float* c2w = (const float*)d_in[16];
    const float* c2b = (const float*)d_in[17];
    const float* wih2 = (const float*)d_in[18];
    const float* whh2 = (const float*)d_in[19];
    const float* bih2 = (const float*)d_in[20];
    const float* bhh2 = (const float*)d_in[21];
    const float* kw = (const float*)d_in[22];
    const float* kb = (const float*)d_in[23];
    const float* vw = (const float*)d_in[24];
    const float* vb = (const float*)d_in[25];
    const float* wihd = (const float*)d_in[26];
    const float* whhd = (const float*)d_in[27];
    const float* bihd = (const float*)d_in[28];
    const float* bhhd = (const float*)d_in[29];
    const float* w1 = (const float*)d_in[30];
    const float* b1 = (const float*)d_in[31];
    const float* w2 = (const float*)d_in[32];
    const float* b2 = (const float*)d_in[33];
    const float* w3 = (const float*)d_in[34];
    const float* b3 = (const float*)d_in[35];
    const float* emb = (const float*)d_in[36];
    const float* sh0 = (const float*)d_in[37];
    const float* sc0 = (const float*)d_in[38];

    // ---- workspace plan (peak <= 160 MiB, stream-ordered reuse) ----
    char* ws = (char*)d_ws;
    const size_t MB = 1ull << 20;
    float* Hf       = (float*)(ws + 0);          // 64 MiB  [t][b][128]
    float* Hr       = (float*)(ws + 64 * MB);    // 64 MiB
    float* conv1out = (float*)(ws + 128 * MB);   // 32 MiB  [b][t'][128]
    float* P2       = (float*)(ws + 0);          // 128 MiB (over Hf+Hr)
    float* H2       = (float*)(ws + 128 * MB);   // 32 MiB  (over conv1out)
    float* conv2out = (float*)(ws + 0);          // 16 MiB  (over P2 head)
    float* P3       = (float*)(ws + 16 * MB);    // 64 MiB
    float* H3       = (float*)(ws + 80 * MB);    // 16 MiB  [t''][b][128]
    float* hkb      = (float*)(ws + 96 * MB);    // 16 MiB  [t''][b][d]
    float* hvT      = (float*)(ws + 112 * MB);   // 16 MiB  [b][d][t''] (dead after pack)
    unsigned int* hvpak = (unsigned int*)(ws + 0); // 8 MiB (over conv2out, dead)
    float* Ypack    = (float*)(ws + 112 * MB);   // 32 MiB  (over hvT after pack)
    float* Yp       = (float*)(ws + 16 * MB);    // 32 MiB  (over P3, dead after lstm3)

    lstm1_k<<<128, 512, 0, stream>>>(utter, wih_f, whh_f, bih_f, bhh_f,
                                     wih_r, whh_r, bih_r, bhh_r, Hf, Hr);
    conv_k<256><<<dim3(64, 32), 128, 0, stream>>>(Hf, Hr, c1w, c1b, conv1out, 1024);
    gemm_k<<<dim3(1024, 8), 256, 0, stream>>>(conv1out, wih1, 128, bih1, bhh1,
                                              P2, 65536, 512, 128, 0, 0);
    lstm_k<<<64, 512, 0, stream>>>(P2, whh1, H2, 1024);
    conv_k<128><<<dim3(64, 16), 128, 0, stream>>>(H2, nullptr, c2w, c2b, conv2out, 512);
    gemm_k<<<dim3(512, 8), 256, 0, stream>>>(conv2out, wih2, 128, bih2, bhh2,
                                             P3, 32768, 512, 128, 0, 0);
    lstm_k<<<64, 512, 0, stream>>>(P3, whh2, H3, 512);
    // hk: [t][b][d] f32 ; hv: transposed [b][d][t] f32 then packed to bf16 pairs
    gemm_k<<<dim3(512, 2), 256, 0, stream>>>(H3, kw, 128, kb, nullptr,
                                             hkb, 32768, 128, 128, 0, 0);
    gemm_k<<<dim3(512, 2), 256, 0, stream>>>(H3, vw, 128, vb, nullptr,
                                             hvT, 32768, 128, 128, 1, 512);
    packhv_k<<<dim3(64, 128), 256, 0, stream>>>(hvT, hvpak);
    // decoder y-path projection (hoisted)
    packemb_k<<<16320, 512, 0, stream>>>(targets, emb, Ypack);
    gemm_k<<<dim3(255, 8), 256, 0, stream>>>(Ypack, wihd, 640, bihd, bhhd,
                                             Yp, 16320, 512, 512, 0, 0);
    decoder_k<<<64, 512, 0, stream>>>(Yp, whhd, wihd, hkb, hvpak,
                                      w1, b1, w2, b2, w3, b3, sh0, sc0,
                                      (float*)d_out);
}

// Round 5
// 5999.183 us; speedup vs baseline: 3.0154x; 3.0154x over previous
//
#include <hip/hip_runtime.h>

// ---------------- types & helpers ----------------
typedef _Float16 half_t;
typedef _Float16 __attribute__((ext_vector_type(2))) half2_t;

__device__ __forceinline__ float fdot2_(half2_t a, half2_t b, float c) {
#if __has_builtin(__builtin_amdgcn_fdot2)
    return __builtin_amdgcn_fdot2(a, b, c, false);
#else
    return c + (float)a[0] * (float)b[0] + (float)a[1] * (float)b[1];
#endif
}
__device__ __forceinline__ half2_t h2(float a, float b) {
    half2_t r; r[0] = (half_t)a; r[1] = (half_t)b; return r;
}
__device__ __forceinline__ half2_t bc2(unsigned int u) {
    return __builtin_bit_cast(half2_t, u);
}
__device__ __forceinline__ float sigm(float x) { return 1.0f / (1.0f + __expf(-x)); }
__device__ __forceinline__ float tanh_(float x) { return 1.0f - 2.0f / (1.0f + __expf(2.0f * x)); }
__device__ __forceinline__ unsigned int packbf2(float a, float b) {
    unsigned int ua = __float_as_uint(a);
    ua = (ua + 0x7fffu + ((ua >> 16) & 1u)) >> 16;
    unsigned int ub = __float_as_uint(b);
    ub = (ub + 0x7fffu + ((ub >> 16) & 1u)) >> 16;
    return ua | (ub << 16);
}
__device__ __forceinline__ float blo(unsigned int u) { return __uint_as_float(u << 16); }
__device__ __forceinline__ float bhi(unsigned int u) { return __uint_as_float(u & 0xffff0000u); }

// ---------------- LSTM layer 1 (bidirectional, K=40 input fused) ----------------
// grid 128 (64 batch x 2 dir), 512 threads. Weights f16-packed: 84 VGPRs/thread -> no spill.
__global__ __launch_bounds__(512) void lstm1_k(
    const float* __restrict__ utter,
    const float* __restrict__ wih_f, const float* __restrict__ whh_f,
    const float* __restrict__ bih_f, const float* __restrict__ bhh_f,
    const float* __restrict__ wih_r, const float* __restrict__ whh_r,
    const float* __restrict__ bih_r, const float* __restrict__ bhh_r,
    float* __restrict__ Hf, float* __restrict__ Hr)
{
    const int tid = threadIdx.x;
    const int b   = blockIdx.x & 63;
    const int dir = blockIdx.x >> 6;
    const float* wih = dir ? wih_r : wih_f;
    const float* whh = dir ? whh_r : whh_f;
    const float* bih = dir ? bih_r : bih_f;
    const float* bhh = dir ? bhh_r : bhh_f;
    float* Hout = dir ? Hr : Hf;

    __shared__ float gates[512];
    __shared__ __align__(16) half_t h_h[128];
    __shared__ __align__(16) half_t x2[3][48];

    const int j = tid;
    half2_t wr2[64];
    {
        const float4* wp = reinterpret_cast<const float4*>(whh + j * 128);
#pragma unroll
        for (int m = 0; m < 32; ++m) {
            float4 v = wp[m];
            wr2[2 * m]     = h2(v.x, v.y);
            wr2[2 * m + 1] = h2(v.z, v.w);
        }
    }
    half2_t wx2[20];
    {
        const float4* xp = reinterpret_cast<const float4*>(wih + j * 40);
#pragma unroll
        for (int q = 0; q < 10; ++q) {
            float4 v = xp[q];
            wx2[2 * q]     = h2(v.x, v.y);
            wx2[2 * q + 1] = h2(v.z, v.w);
        }
    }
    const float bias = bih[j] + bhh[j];
    float c = 0.0f;
    if (tid < 128) h_h[tid] = (half_t)0.0f;
    if (tid < 40) {
        int tt0 = dir ? 2047 : 0;
        x2[0][tid] = (half_t)utter[((size_t)b * 2048 + tt0) * 40 + tid];
    } else if (tid < 80) {
        int tt1 = dir ? 2046 : 1;
        x2[1][tid - 40] = (half_t)utter[((size_t)b * 2048 + tt1) * 40 + (tid - 40)];
    }
    __syncthreads();

    for (int t = 0; t < 2048; ++t) {
        const int cur = t % 3;
        const int nx2 = (t + 2) % 3;
        float xn = 0.0f;
        const int tq = tid - 128;
        if (tq >= 0 && tq < 40) {
            int tn = (t + 2 < 2048) ? (t + 2) : 2047;
            int ttn = dir ? (2047 - tn) : tn;
            xn = utter[((size_t)b * 2048 + ttn) * 40 + tq];
        }
        float g0 = bias, g1 = 0.f, g2 = 0.f, g3 = 0.f;
        {
            const uint4* x4p = reinterpret_cast<const uint4*>(&x2[cur][0]);
#pragma unroll
            for (int q = 0; q < 5; ++q) {
                uint4 u = x4p[q];
                g0 = fdot2_(wx2[4 * q],     bc2(u.x), g0);
                g1 = fdot2_(wx2[4 * q + 1], bc2(u.y), g1);
                g2 = fdot2_(wx2[4 * q + 2], bc2(u.z), g2);
                g3 = fdot2_(wx2[4 * q + 3], bc2(u.w), g3);
            }
            const uint4* h4p = reinterpret_cast<const uint4*>(h_h);
#pragma unroll
            for (int q = 0; q < 16; ++q) {
                uint4 u = h4p[q];
                g0 = fdot2_(wr2[4 * q],     bc2(u.x), g0);
                g1 = fdot2_(wr2[4 * q + 1], bc2(u.y), g1);
                g2 = fdot2_(wr2[4 * q + 2], bc2(u.z), g2);
                g3 = fdot2_(wr2[4 * q + 3], bc2(u.w), g3);
            }
        }
        gates[j] = (g0 + g1) + (g2 + g3);
        __syncthreads();
        if (tid < 128) {
            float i_ = sigm(gates[tid]);
            float f_ = sigm(gates[128 + tid]);
            float g_ = tanh_(gates[256 + tid]);
            float o_ = sigm(gates[384 + tid]);
            c = f_ * c + i_ * g_;
            float hh = o_ * tanh_(c);
            h_h[tid] = (half_t)hh;
            int tt = dir ? (2047 - t) : t;
            Hout[((size_t)tt * 64 + b) * 128 + tid] = hh;
        } else if (tq < 40) {
            x2[nx2][tq] = (half_t)xn;
        }
        __syncthreads();
    }
}

// ---------------- LSTM layers 2/3 (P precomputed incl. biases) ----------------
__global__ __launch_bounds__(512) void lstm_k(
    const float* __restrict__ P, const float* __restrict__ whh,
    float* __restrict__ Hout, int T)
{
    const int tid = threadIdx.x;
    const int b = blockIdx.x;
    const int j = tid;
    __shared__ float gates[512];
    __shared__ __align__(16) half_t h_h[128];
    half2_t wr2[64];
    {
        const float4* wp = reinterpret_cast<const float4*>(whh + j * 128);
#pragma unroll
        for (int m = 0; m < 32; ++m) {
            float4 v = wp[m];
            wr2[2 * m]     = h2(v.x, v.y);
            wr2[2 * m + 1] = h2(v.z, v.w);
        }
    }
    float c = 0.0f;
    if (tid < 128) h_h[tid] = (half_t)0.0f;
    float p_cur = P[((size_t)b * T + 0) * 512 + j];
    float p_n1  = P[((size_t)b * T + ((T > 1) ? 1 : 0)) * 512 + j];
    __syncthreads();
    for (int t = 0; t < T; ++t) {
        int tn = (t + 2 < T) ? (t + 2) : (T - 1);
        float p_n2 = P[((size_t)b * T + tn) * 512 + j];
        float g0 = p_cur, g1 = 0.f, g2 = 0.f, g3 = 0.f;
        const uint4* h4p = reinterpret_cast<const uint4*>(h_h);
#pragma unroll
        for (int q = 0; q < 16; ++q) {
            uint4 u = h4p[q];
            g0 = fdot2_(wr2[4 * q],     bc2(u.x), g0);
            g1 = fdot2_(wr2[4 * q + 1], bc2(u.y), g1);
            g2 = fdot2_(wr2[4 * q + 2], bc2(u.z), g2);
            g3 = fdot2_(wr2[4 * q + 3], bc2(u.w), g3);
        }
        gates[j] = (g0 + g1) + (g2 + g3);
        __syncthreads();
        if (tid < 128) {
            float i_ = sigm(gates[tid]);
            float f_ = sigm(gates[128 + tid]);
            float g_ = tanh_(gates[256 + tid]);
            float o_ = sigm(gates[384 + tid]);
            c = f_ * c + i_ * g_;
            float hh = o_ * tanh_(c);
            h_h[tid] = (half_t)hh;
            Hout[((size_t)t * 64 + b) * 128 + tid] = hh;
        }
        __syncthreads();
        p_cur = p_n1;
        p_n1 = p_n2;
    }
}

// ---------------- conv1d kernel=2 stride=2 ----------------
template <int CIN>
__global__ __launch_bounds__(128) void conv_k(
    const float* __restrict__ HA, const float* __restrict__ HB,
    const float* __restrict__ W, const float* __restrict__ bias,
    float* __restrict__ out, int Tout)
{
    __shared__ __align__(16) float xin[64 * CIN];
    const int b = blockIdx.x;
    const int t0 = blockIdx.y * 32;
    const int tid = threadIdx.x;
    for (int idx = tid; idx < 64 * CIN; idx += 128) {
        int tl = idx / CIN, ci = idx % CIN;
        int tau = t0 * 2 + tl;
        float v;
        if constexpr (CIN == 256) {
            v = (ci < 128) ? HA[(size_t)tau * 8192 + b * 128 + ci]
                           : HB[(size_t)tau * 8192 + b * 128 + (ci - 128)];
        } else {
            v = HA[(size_t)tau * 8192 + b * 128 + ci];
        }
        xin[idx] = v;
    }
    __syncthreads();
    const int co = tid;
    float acc[32];
#pragma unroll
    for (int u = 0; u < 32; ++u) acc[u] = 0.0f;
    const float4* Wrow4 = reinterpret_cast<const float4*>(W + (size_t)co * 2 * CIN);
    const float4* xin4 = reinterpret_cast<const float4*>(xin);
    for (int c4 = 0; c4 < CIN / 4; ++c4) {
        float4 wA = Wrow4[2 * c4];
        float4 wB = Wrow4[2 * c4 + 1];
#pragma unroll
        for (int u = 0; u < 32; ++u) {
            float4 x0 = xin4[(2 * u) * (CIN / 4) + c4];
            float4 x1 = xin4[(2 * u + 1) * (CIN / 4) + c4];
            acc[u] += wA.x * x0.x + wA.y * x1.x + wA.z * x0.y + wA.w * x1.y
                    + wB.x * x0.z + wB.y * x1.z + wB.z * x0.w + wB.w * x1.w;
        }
    }
    float bs = bias[co];
#pragma unroll
    for (int u = 0; u < 32; ++u)
        out[((size_t)b * Tout + t0 + u) * 128 + co] = acc[u] + bs;
}

// ---------------- generic f32 GEMM ----------------
__global__ __launch_bounds__(256) void gemm_k(
    const float* __restrict__ A, const float* __restrict__ W, int ldw,
    const float* __restrict__ bias1, const float* __restrict__ bias2,
    float* __restrict__ C, int M, int N, int K, int mode, int Tdim)
{
    __shared__ __align__(16) float As[16][68];
    __shared__ __align__(16) float Ws[16][68];
    const int tid = threadIdx.x;
    const int m0 = blockIdx.x * 64, n0 = blockIdx.y * 64;
    const int kk = tid & 15, mm = tid >> 4;
    const int tm = tid & 15, tn = tid >> 4;
    float acc[4][4];
#pragma unroll
    for (int i = 0; i < 4; ++i)
#pragma unroll
        for (int jj = 0; jj < 4; ++jj) acc[i][jj] = 0.0f;

    for (int k0 = 0; k0 < K; k0 += 16) {
#pragma unroll
        for (int r = 0; r < 4; ++r) {
            As[kk][mm + 16 * r] = A[(size_t)(m0 + mm + 16 * r) * K + k0 + kk];
            Ws[kk][mm + 16 * r] = W[(size_t)(n0 + mm + 16 * r) * ldw + k0 + kk];
        }
        __syncthreads();
#pragma unroll
        for (int q = 0; q < 16; ++q) {
            float4 a = reinterpret_cast<const float4*>(&As[q][0])[tm];
            float4 w = reinterpret_cast<const float4*>(&Ws[q][0])[tn];
            acc[0][0] += a.x * w.x; acc[0][1] += a.x * w.y; acc[0][2] += a.x * w.z; acc[0][3] += a.x * w.w;
            acc[1][0] += a.y * w.x; acc[1][1] += a.y * w.y; acc[1][2] += a.y * w.z; acc[1][3] += a.y * w.w;
            acc[2][0] += a.z * w.x; acc[2][1] += a.z * w.y; acc[2][2] += a.z * w.z; acc[2][3] += a.z * w.w;
            acc[3][0] += a.w * w.x; acc[3][1] += a.w * w.y; acc[3][2] += a.w * w.z; acc[3][3] += a.w * w.w;
        }
        __syncthreads();
    }
    float bv[4];
#pragma unroll
    for (int jj = 0; jj < 4; ++jj) {
        int n = n0 + tn * 4 + jj;
        float v = 0.0f;
        if (bias1) v += bias1[n];
        if (bias2) v += bias2[n];
        bv[jj] = v;
    }
#pragma unroll
    for (int i = 0; i < 4; ++i) {
        int m = m0 + tm * 4 + i;
#pragma unroll
        for (int jj = 0; jj < 4; ++jj) {
            int n = n0 + tn * 4 + jj;
            float v = acc[i][jj] + bv[jj];
            if (mode == 0) {
                C[(size_t)m * N + n] = v;
            } else {
                int bb = m & 63, tt = m >> 6;
                C[((size_t)bb * N + n) * Tdim + tt] = v;
            }
        }
    }
}

// ---------------- gather emb[targets] rows ----------------
__global__ __launch_bounds__(512) void packemb_k(
    const int* __restrict__ targets, const float* __restrict__ emb,
    float* __restrict__ Ypack)
{
    int m = blockIdx.x;  // l*64 + b
    int l = m >> 6, b = m & 63;
    int tgt = targets[b * 256 + l];
    Ypack[(size_t)m * 512 + threadIdx.x] = emb[(size_t)tgt * 512 + threadIdx.x];
}

// ---------------- attention decoder v4: 64 blocks x 1024 threads ----------------
// Role-split gate phase (waves 0-7: sh@whhd, waves 8-15: c@wc), f16 dot2 weights
// in regs (64/thread), hk bf16 in LDS (f32 score math), hv f32 streamed from L2.
__global__ __launch_bounds__(1024) void decoder_k(
    const float* __restrict__ Yp, const float* __restrict__ whhd, const float* __restrict__ wihd,
    const float* __restrict__ hk,  // f32 [t*64+b][128]
    const float* __restrict__ hv,  // f32 [t*64+b][128]
    const float* __restrict__ w1, const float* __restrict__ b1,
    const float* __restrict__ w2, const float* __restrict__ b2,
    const float* __restrict__ w3, const float* __restrict__ b3,
    const float* __restrict__ sh0, const float* __restrict__ sc0,
    float* __restrict__ out)
{
    __shared__ unsigned int hk_lds[512][66];        // 135168 B, bf16 pairs
    __shared__ __align__(16) float partial[32][128]; // 16 KiB (ph1 flat 1024 / ph4 tiles)
    __shared__ __align__(16) float sh_f[128];
    __shared__ __align__(16) half_t sh_h[128];
    __shared__ __align__(16) float sc_f[128];
    __shared__ __align__(16) float c_f[128];
    __shared__ __align__(16) half_t c_h[128];
    __shared__ __align__(16) float att[512];
    __shared__ float red[8];
    __shared__ float pa[34], pb[34], z_lds[34];
    __shared__ float w3_lds[34 * 34];
    __shared__ float b3_lds[34];

    const int tid = threadIdx.x;
    const int b = blockIdx.x;
    const int role = tid >> 9;       // wave-uniform
    const int j = tid & 511;
    float* pflat = &partial[0][0];

    // weights: role0 = whhd row j ; role1 = wihd row j, cols 512..639 (c-path)
    half2_t w2r[64];
    {
        const float4* wp = role
            ? reinterpret_cast<const float4*>(wihd + (size_t)j * 640 + 512)
            : reinterpret_cast<const float4*>(whhd + (size_t)j * 128);
#pragma unroll
        for (int m = 0; m < 32; ++m) {
            float4 v = wp[m];
            w2r[2 * m]     = h2(v.x, v.y);
            w2r[2 * m + 1] = h2(v.z, v.w);
        }
    }
    // hk preload: thread (t=j, half=role) -> bf16 pairs in LDS
    {
        const float4* hp = reinterpret_cast<const float4*>(hk + ((size_t)j * 64 + b) * 128 + role * 64);
#pragma unroll
        for (int q = 0; q < 16; ++q) {
            float4 v = hp[q];
            hk_lds[j][role * 32 + 2 * q]     = packbf2(v.x, v.y);
            hk_lds[j][role * 32 + 2 * q + 1] = packbf2(v.z, v.w);
        }
    }
    for (int idx = tid; idx < 34 * 34; idx += 1024) w3_lds[idx] = w3[idx];
    if (tid < 34) b3_lds[tid] = b3[tid];
    float sc_r = 0.0f;
    if (tid < 128) {
        float s = sh0[b * 128 + tid];
        sh_f[tid] = s; sh_h[tid] = (half_t)s;
        sc_r = sc0[b * 128 + tid];
        sc_f[tid] = sc_r;
        c_f[tid] = 0.0f; c_h[tid] = (half_t)0.0f;
    }
    __syncthreads();

    const int wid = tid >> 6, lane = tid & 63;
    const int tg = tid >> 5, dq = tid & 31;          // phase-4 mapping
    float yp_cur = (role == 0) ? Yp[(size_t)b * 512 + j] : 0.0f;

    for (int l = 0; l < 255; ++l) {
        int lnxt = (l + 1 < 255) ? (l + 1) : l;
        float yp_nxt = (role == 0) ? Yp[((size_t)lnxt * 64 + b) * 512 + j] : 0.0f;
        // ---- phase 1: partial gate dots (f16 dot2)
        {
            const uint4* s4 = reinterpret_cast<const uint4*>(role ? c_h : sh_h);
            float g0 = yp_cur, g1 = 0.f, g2 = 0.f, g3 = 0.f;
#pragma unroll
            for (int q = 0; q < 16; ++q) {
                uint4 u = s4[q];
                g0 = fdot2_(w2r[4 * q],     bc2(u.x), g0);
                g1 = fdot2_(w2r[4 * q + 1], bc2(u.y), g1);
                g2 = fdot2_(w2r[4 * q + 2], bc2(u.z), g2);
                g3 = fdot2_(w2r[4 * q + 3], bc2(u.w), g3);
            }
            pflat[tid] = (g0 + g1) + (g2 + g3);
        }
        __syncthreads();                                   // B1
        // ---- phase 2: cell update
        if (tid < 128) {
            float i_ = sigm(pflat[tid]       + pflat[512 + tid]);
            float f_ = sigm(pflat[128 + tid] + pflat[640 + tid]);
            float g_ = tanh_(pflat[256 + tid] + pflat[768 + tid]);
            float o_ = sigm(pflat[384 + tid] + pflat[896 + tid]);
            sc_r = f_ * sc_r + i_ * g_;
            float hh = o_ * tanh_(sc_r);
            sh_f[tid] = hh; sh_h[tid] = (half_t)hh;
            sc_f[tid] = sc_r;
        }
        __syncthreads();                                   // B2
        // ---- phase 3: scores over 512 positions (threads 0..511), bf16 hk x f32 sc
        if (tid < 512) {
            float e0 = 0.f, e1 = 0.f, e2 = 0.f, e3 = 0.f;
            const uint2* hkr = reinterpret_cast<const uint2*>(&hk_lds[tid][0]);
            const float4* sc4 = reinterpret_cast<const float4*>(sc_f);
#pragma unroll
            for (int q = 0; q < 32; ++q) {
                uint2 u = hkr[q];
                float4 s = sc4[q];
                e0 += blo(u.x) * s.x; e1 += bhi(u.x) * s.y;
                e2 += blo(u.y) * s.z; e3 += bhi(u.y) * s.w;
            }
            float p = __expf((e0 + e1) + (e2 + e3));
            att[tid] = p;
            float ps = p;
#pragma unroll
            for (int off = 32; off; off >>= 1) ps += __shfl_xor(ps, off);
            if (lane == 0) red[wid] = ps;
        }
        __syncthreads();                                   // B3
        // ---- phase 4: context partials; thread (tg, dq): 16 t-rows, 4 d's
        {
            const float* hvp = hv + ((size_t)(tg * 16) * 64 + b) * 128 + dq * 4;
            float4 a = make_float4(0.f, 0.f, 0.f, 0.f);
#pragma unroll 4
            for (int tt = 0; tt < 16; ++tt) {
                float w = att[tg * 16 + tt];
                float4 v = *reinterpret_cast<const float4*>(hvp + (size_t)tt * 8192);
                a.x += w * v.x; a.y += w * v.y; a.z += w * v.z; a.w += w * v.w;
            }
            *reinterpret_cast<float4*>(&partial[tg][dq * 4]) = a;
        }
        __syncthreads();                                   // B4
        if (tid < 128) {
            float S = ((red[0] + red[1]) + (red[2] + red[3]))
                    + ((red[4] + red[5]) + (red[6] + red[7]));
            float cs = 0.f;
#pragma unroll
            for (int g = 0; g < 32; ++g) cs += partial[g][tid];
            float cv = cs / S;
            c_f[tid] = cv; c_h[tid] = (half_t)cv;
        }
        __syncthreads();                                   // B5
        // ---- phase 5a: w1.sh (wave0) and w2.c (wave1) in parallel
        if (tid < 34) {
            float o1 = b1[tid];
            const float4* w1r = reinterpret_cast<const float4*>(w1 + tid * 128);
            const float4* sh4 = reinterpret_cast<const float4*>(sh_f);
#pragma unroll 8
            for (int q = 0; q < 32; ++q) {
                float4 a = w1r[q], h = sh4[q];
                o1 += a.x * h.x + a.y * h.y + a.z * h.z + a.w * h.w;
            }
            pa[tid] = o1;
        } else if (tid >= 64 && tid < 98) {
            int v = tid - 64;
            float o2 = b2[v];
            const float4* w2p = reinterpret_cast<const float4*>(w2 + v * 128);
            const float4* c4 = reinterpret_cast<const float4*>(c_f);
#pragma unroll 8
            for (int q = 0; q < 32; ++q) {
                float4 a = w2p[q], cc = c4[q];
                o2 += a.x * cc.x + a.y * cc.y + a.z * cc.z + a.w * cc.w;
            }
            pb[v] = o2;
        }
        __syncthreads();                                   // B6
        if (tid < 34) {
            float z = b3_lds[tid];
            const float* w3r = &w3_lds[tid * 34];
            for (int v = 0; v < 34; ++v) z += w3r[v] * fmaxf(pa[v] + pb[v], 0.0f);
            z_lds[tid] = z;
        }
        __syncthreads();                                   // B7
        if (tid < 34) {
            float zm = z_lds[0];
            for (int v = 1; v < 34; ++v) zm = fmaxf(zm, z_lds[v]);
            float Ssum = 0.0f;
            for (int v = 0; v < 34; ++v) Ssum += __expf(z_lds[v] - zm);
            out[((size_t)b * 255 + l) * 34 + tid] = __expf(z_lds[tid] - zm) / Ssum;
        }
        yp_cur = yp_nxt;
        __syncthreads();                                   // B8 (protect pflat/att reuse)
    }
}

// ---------------- launch ----------------
extern "C" void kernel_launch(void* const* d_in, const int* in_sizes, int n_in,
                              void* d_out, int out_size, void* d_ws, size_t ws_size,
                              hipStream_t stream) {
    (void)in_sizes; (void)n_in; (void)out_size; (void)ws_size;
    const float* utter = (const float*)d_in[0];
    const int*   targets = (const int*)d_in[1];
    const float* wih_f = (const float*)d_in[2];
    const float* whh_f = (const float*)d_in[3];
    const float* bih_f = (const float*)d_in[4];
    const float* bhh_f = (const float*)d_in[5];
    const float* wih_r = (const float*)d_in[6];
    const float* whh_r = (const float*)d_in[7];
    const float* bih_r = (const float*)d_in[8];
    const float* bhh_r = (const float*)d_in[9];
    const float* c1w = (const float*)d_in[10];
    const float* c1b = (const float*)d_in[11];
    const float* wih1 = (const float*)d_in[12];
    const float* whh1 = (const float*)d_in[13];
    const float* bih1 = (const float*)d_in[14];
    const float* bhh1 = (const float*)d_in[15];
    const float* c2w = (const float*)d_in[16];
    const float* c2b = (const float*)d_in[17];
    const float* wih2 = (const float*)d_in[18];
    const float* whh2 = (const float*)d_in[19];
    const float* bih2 = (const float*)d_in[20];
    const float* bhh2 = (const float*)d_in[21];
    const float* kw = (const float*)d_in[22];
    const float* kb = (const float*)d_in[23];
    const float* vw = (const float*)d_in[24];
    const float* vb = (const float*)d_in[25];
    const float* wihd = (const float*)d_in[26];
    const float* whhd = (const float*)d_in[27];
    const float* bihd = (const float*)d_in[28];
    const float* bhhd = (const float*)d_in[29];
    const float* w1 = (const float*)d_in[30];
    const float* b1 = (const float*)d_in[31];
    const float* w2 = (const float*)d_in[32];
    const float* b2 = (const float*)d_in[33];
    const float* w3 = (const float*)d_in[34];
    const float* b3 = (const float*)d_in[35];
    const float* emb = (const float*)d_in[36];
    const float* sh0 = (const float*)d_in[37];
    const float* sc0 = (const float*)d_in[38];

    // ---- workspace plan (peak <= 160 MiB, stream-ordered reuse) ----
    char* ws = (char*)d_ws;
    const size_t MB = 1ull << 20;
    float* Hf       = (float*)(ws + 0);          // 64 MiB  [t][b][128]
    float* Hr       = (float*)(ws + 64 * MB);    // 64 MiB
    float* conv1out = (float*)(ws + 128 * MB);   // 32 MiB  [b][t'][128]
    float* P2       = (float*)(ws + 0);          // 128 MiB (over Hf+Hr)
    float* H2       = (float*)(ws + 128 * MB);   // 32 MiB  (over conv1out)
    float* conv2out = (float*)(ws + 0);          // 16 MiB  (over P2 head)
    float* P3       = (float*)(ws + 16 * MB);    // 64 MiB
    float* H3       = (float*)(ws + 80 * MB);    // 16 MiB  [t''][b][128]
    float* hkb      = (float*)(ws + 96 * MB);    // 16 MiB  [t''][b][d]
    float* hvb      = (float*)(ws + 112 * MB);   // 16 MiB  [t''][b][d]
    float* Ypack    = (float*)(ws + 128 * MB);   // 32 MiB  (over H2, dead after conv2)
    float* Yp       = (float*)(ws + 16 * MB);    // 32 MiB  (over P3, dead after lstm3)

    lstm1_k<<<128, 512, 0, stream>>>(utter, wih_f, whh_f, bih_f, bhh_f,
                                     wih_r, whh_r, bih_r, bhh_r, Hf, Hr);
    conv_k<256><<<dim3(64, 32), 128, 0, stream>>>(Hf, Hr, c1w, c1b, conv1out, 1024);
    gemm_k<<<dim3(1024, 8), 256, 0, stream>>>(conv1out, wih1, 128, bih1, bhh1,
                                              P2, 65536, 512, 128, 0, 0);
    lstm_k<<<64, 512, 0, stream>>>(P2, whh1, H2, 1024);
    conv_k<128><<<dim3(64, 16), 128, 0, stream>>>(H2, nullptr, c2w, c2b, conv2out, 512);
    gemm_k<<<dim3(512, 8), 256, 0, stream>>>(conv2out, wih2, 128, bih2, bhh2,
                                             P3, 32768, 512, 128, 0, 0);
    lstm_k<<<64, 512, 0, stream>>>(P3, whh2, H3, 512);
    gemm_k<<<dim3(512, 2), 256, 0, stream>>>(H3, kw, 128, kb, nullptr,
                                             hkb, 32768, 128, 128, 0, 0);
    gemm_k<<<dim3(512, 2), 256, 0, stream>>>(H3, vw, 128, vb, nullptr,
                                             hvb, 32768, 128, 128, 0, 0);
    packemb_k<<<16320, 512, 0, stream>>>(targets, emb, Ypack);
    gemm_k<<<dim3(255, 8), 256, 0, stream>>>(Ypack, wihd, 640, bihd, bhhd,
                                             Yp, 16320, 512, 512, 0, 0);
    decoder_k<<<64, 1024, 0, stream>>>(Yp, whhd, wihd, hkb, hvb,
                                       w1, b1, w2, b2, w3, b3, sh0, sc0,
                                       (float*)d_out);
}